// Round 15
// baseline (250.137 us; speedup 1.0000x reference)
//
#include <hip/hip_runtime.h>
#include <hip/hip_bf16.h>

// Problem dims (fixed by the reference)
#define BB 4
#define TT 2048
#define HH 1024
#define NHH 16
#define DKK 64
// M = BB*TT = 8192, K = N = HH = 1024

typedef __attribute__((ext_vector_type(8))) short bf16x8;
typedef __attribute__((ext_vector_type(4))) float f32x4;

__device__ __forceinline__ unsigned short f2bf(float f) {
    union { float f; unsigned u; } v; v.f = f;
    unsigned r = v.u + 0x7fffu + ((v.u >> 16) & 1u);  // RNE
    return (unsigned short)(r >> 16);
}

__device__ __forceinline__ bf16x8 cvt8(const float* __restrict__ p) {
    float4 a = *(const float4*)p;
    float4 b = *(const float4*)(p + 4);
    bf16x8 r;
    r[0] = (short)f2bf(a.x); r[1] = (short)f2bf(a.y);
    r[2] = (short)f2bf(a.z); r[3] = (short)f2bf(a.w);
    r[4] = (short)f2bf(b.x); r[5] = (short)f2bf(b.y);
    r[6] = (short)f2bf(b.z); r[7] = (short)f2bf(b.w);
    return r;
}

// async global->LDS, 16B per lane; LDS dest must be linear in lane order
__device__ __forceinline__ void gload_lds16(const unsigned short* g, unsigned short* l) {
    __builtin_amdgcn_global_load_lds(
        (const __attribute__((address_space(1))) unsigned int*)g,
        (__attribute__((address_space(3))) unsigned int*)l, 16, 0, 0);
}

// ---------------- weight transpose + convert, all 6 weights, 64x64 tiles, coalesced ----------------
__global__ __launch_bounds__(256) void wtcvt6_kernel(
    const float* __restrict__ W0, const float* __restrict__ W1, const float* __restrict__ W2,
    const float* __restrict__ W3, const float* __restrict__ W4, const float* __restrict__ W5,
    unsigned short* __restrict__ T0, unsigned short* __restrict__ T1, unsigned short* __restrict__ T2,
    unsigned short* __restrict__ T3, unsigned short* __restrict__ T4, unsigned short* __restrict__ T5) {
    const float* W; unsigned short* Wt;
    switch (blockIdx.z) {
        case 0: W = W0; Wt = T0; break;
        case 1: W = W1; Wt = T1; break;
        case 2: W = W2; Wt = T2; break;
        case 3: W = W3; Wt = T3; break;
        case 4: W = W4; Wt = T4; break;
        default: W = W5; Wt = T5; break;
    }
    __shared__ float t[64][65];
    int bx = blockIdx.x * 64, by = blockIdx.y * 64;   // bx: n-range, by: k-range
    int tx = threadIdx.x, ty = threadIdx.y;           // block (32,8)
#pragma unroll
    for (int i = 0; i < 8; i++) {
        int kk = ty + 8 * i;
        float2 v = *(const float2*)&W[(size_t)(by + kk) * HH + bx + 2 * tx];
        t[kk][2 * tx] = v.x;
        t[kk][2 * tx + 1] = v.y;
    }
    __syncthreads();
#pragma unroll
    for (int i = 0; i < 8; i++) {
        int nn = ty + 8 * i;
        unsigned u = (unsigned)f2bf(t[2 * tx][nn]) | ((unsigned)f2bf(t[2 * tx + 1][nn]) << 16);
        *(unsigned*)&Wt[(size_t)(bx + nn) * HH + by + 2 * tx] = u;  // Wt[n][k] = W[k][n]
    }
}

// ---------------- MFMA GEMM (m97 structure): 128x128 tile, BK=64, global_load_lds w=16 ----------------
// Grid FIXED (8,64), in-kernel XCD tile swizzle (column-blocks sharing an A panel -> same XCD).
// F32A: A is fp32, reg-staged + converted in-register (no separate cvt pass).
// EPI: 1=relu->bf16  2=source-mask->bf16  3=head-split (K)  5=+resid fp32 out
//      6=head-split * 0.125*log2e (Q)
//      4=transposed-head (V): MFMA operands SWAPPED -> D[n][m], so the Vt store has lane
//        varying t -> 32B-contiguous writes (was 2B scatter at 4KB stride).
template <int EPI, bool SKIP, bool F32A>
__global__ __launch_bounds__(256) void gemm_kernel(
    const unsigned short* __restrict__ A16, const float* __restrict__ A32,
    const unsigned short* __restrict__ Bt,
    const float* __restrict__ bias, unsigned short* __restrict__ Cb,
    float* __restrict__ Cf, const float* __restrict__ resid,
    const int* __restrict__ slen, int M, int N, int K) {
    __shared__ unsigned short As[128 * 64];   // [row][k] linear
    __shared__ unsigned short Bs[128 * 64];
    // XCD swizzle (bijective for 8x64 grid): xcd = flat&7 owns rows {xcd, xcd+8, ...}
    int flat = blockIdx.y * 8 + blockIdx.x;
    int xcd = flat & 7, idx = flat >> 3;
    int bx = (idx & 7) * 128;
    int by = (xcd + ((idx >> 3) << 3)) * 128;
    if constexpr (SKIP) {
        int slb = slen[by >> 11];
        int ktend = ((slb + 63) >> 6) << 6;
        if (ktend == 0) ktend = 64;           // attention still reads tile 0 (uniform-softmax case)
        if ((by & (TT - 1)) >= ktend) return; // whole 128-row tile dead (2048 % 128 == 0)
    }
    int tid = threadIdx.x, lane = tid & 63, w = tid >> 6;
    int wr = (w >> 1) * 64, wc = (w & 1) * 64;     // wave's 64x64 output quadrant

    f32x4 acc[4][4] = {};
    for (int k0 = 0; k0 < K; k0 += 64) {
        __syncthreads();
#pragma unroll
        for (int c = 0; c < 4; c++) {
            int idx2 = c * 256 + tid;
            int r = idx2 >> 3, col = (idx2 & 7) * 8;
            if constexpr (F32A) {
                *(bf16x8*)&As[idx2 * 8] = cvt8(&A32[(size_t)(by + r) * K + k0 + col]);
            } else {
                gload_lds16(&A16[(size_t)(by + r) * K + k0 + col], &As[idx2 * 8]);
            }
            gload_lds16(&Bt[(size_t)(bx + r) * K + k0 + col], &Bs[idx2 * 8]);
        }
        __syncthreads();  // drains vmcnt(0) + lgkmcnt
#pragma unroll
        for (int kk = 0; kk < 2; kk++) {
            bf16x8 a[4], b[4];
#pragma unroll
            for (int i = 0; i < 4; i++)
                a[i] = *(bf16x8*)&As[(wr + i * 16 + (lane & 15)) * 64 + kk * 32 + (lane >> 4) * 8];
#pragma unroll
            for (int j = 0; j < 4; j++)
                b[j] = *(bf16x8*)&Bs[(wc + j * 16 + (lane & 15)) * 64 + kk * 32 + (lane >> 4) * 8];
#pragma unroll
            for (int i = 0; i < 4; i++)
#pragma unroll
                for (int j = 0; j < 4; j++) {
                    if constexpr (EPI == 4)
                        acc[i][j] = __builtin_amdgcn_mfma_f32_16x16x32_bf16(b[j], a[i], acc[i][j], 0, 0, 0);
                    else
                        acc[i][j] = __builtin_amdgcn_mfma_f32_16x16x32_bf16(a[i], b[j], acc[i][j], 0, 0, 0);
                }
        }
    }

    int sl = 0;
    if constexpr (EPI == 2) sl = slen[by >> 11];  // 128-row tile never crosses a batch
#pragma unroll
    for (int i = 0; i < 4; i++)
#pragma unroll
        for (int j = 0; j < 4; j++)
#pragma unroll
            for (int r = 0; r < 4; r++) {
                if constexpr (EPI == 4) {
                    // swapped D: row-dim = n (from b[j]), col-dim = m (from a[i])
                    int nrow = bx + wc + j * 16 + (lane >> 4) * 4 + r;
                    int mcol = by + wr + i * 16 + (lane & 15);
                    float v = acc[i][j][r] + bias[nrow];
                    int b = mcol >> 11, t = mcol & (TT - 1), h = nrow >> 6, d = nrow & 63;
                    Cb[((size_t)((b * NHH + h) * DKK + d)) * TT + t] = f2bf(v);
                } else {
                    int row = by + wr + i * 16 + (lane >> 4) * 4 + r;
                    int col = bx + wc + j * 16 + (lane & 15);
                    float v = acc[i][j][r] + bias[col];
                    if constexpr (EPI == 1) v = fmaxf(v, 0.f);
                    if constexpr (EPI == 2) { int t = row & (TT - 1); if (t >= sl) v = 0.f; }
                    if constexpr (EPI == 6) v *= 0.18033688f;   // 0.125 * log2(e)
                    if constexpr (EPI == 1 || EPI == 2) {
                        Cb[(size_t)row * N + col] = f2bf(v);
                    } else if constexpr (EPI == 3 || EPI == 6) {
                        int b = row >> 11, t = row & (TT - 1), h = col >> 6, d = col & 63;
                        Cb[((size_t)((b * NHH + h) * TT + t)) * DKK + d] = f2bf(v);
                    } else if constexpr (EPI == 5) {
                        Cf[(size_t)row * N + col] = v + resid[(size_t)row * N + col];
                    }
                }
            }
}

// ---------------- flash attention: block = (b, h, 128 q-rows), 8 waves x 16 q-rows ----------------
// r14 config + K/V DOUBLE-BUFFER, ONE barrier per tile: stage t+1 issued right after the
// barrier, drained at the NEXT barrier -> HBM latency (~900cyc, FETCH mostly HBM at 1.2TB/s)
// hides under the whole compute phase instead of being exposed between the old barrier pair.
// 2D grid (per-CU batch mix = load balance; the 1D XCD decode cost ~17us, r11 vs r12).
__global__ __launch_bounds__(512, 6) void attn_kernel(
    const unsigned short* __restrict__ Q, const unsigned short* __restrict__ K,
    const unsigned short* __restrict__ Vt, const int* __restrict__ slen,
    unsigned short* __restrict__ ctx) {
    __shared__ unsigned short Ks[2][64 * 64];     // [kv][dk], XOR-swizzled content
    __shared__ unsigned short Vs[2][64 * 64];     // [dk][kv], XOR-swizzled content
    __shared__ unsigned short Pl[8][16 * 64];     // per-wave P [q][kv], XOR-swizzled
    int tid = threadIdx.x, lane = tid & 63, w = tid >> 6;
    int c = lane & 15, g = lane >> 4;
    int b = blockIdx.z, h = blockIdx.y, q0 = blockIdx.x * 128;
    size_t bhs = (size_t)(b * NHH + h);
    int sl = slen[b];
    int ktend = ((sl + 63) >> 6) << 6;
    if (ktend == 0) ktend = 64;                   // all-masked: one tile, uniform softmax -> bv

    bf16x8 qf[2];                                 // B-operand: Q[q = w*16+c][dk]
    int qrow = q0 + w * 16 + c;
#pragma unroll
    for (int half = 0; half < 2; half++)
        qf[half] = *(const bf16x8*)&Q[(bhs * TT + qrow) * DKK + half * 32 + g * 8];

    char* Pw = (char*)&Pl[w][0];
    unsigned swz = (unsigned)((c & 7) << 4);

    // staging coords: thread stages chunk (r = tid>>3, slot = tid&7) of both K and V;
    // source slot pre-swizzled so LDS[r][s] = G[r][s ^ (r&7)]
    int sr = tid >> 3, ss = tid & 7;
    int scol = (ss ^ (sr & 7)) * 8;

    // prologue: issue tile-0 loads into buffer 0 (drained by the loop's first barrier)
    gload_lds16(&K[(bhs * TT + sr) * DKK + scol], &Ks[0][tid * 8]);
    gload_lds16(&Vt[(bhs * DKK + sr) * TT + scol], &Vs[0][tid * 8]);
    int cur = 0;

    float m_ = -INFINITY, l_ = 0.f;               // state for q-row (w*16 + c), log2 domain
    f32x4 o[4] = {};                              // O[q = g*4+r][d = go*16+c]

    for (int kt = 0; kt < ktend; kt += 64) {
        __syncthreads();   // drains vmcnt -> buf[cur] ready; all waves done reading buf[cur^1]
        if (kt + 64 < ktend) {                    // prefetch next tile into the other buffer
            gload_lds16(&K[(bhs * TT + kt + 64 + sr) * DKK + scol], &Ks[cur ^ 1][tid * 8]);
            gload_lds16(&Vt[(bhs * DKK + sr) * TT + kt + 64 + scol], &Vs[cur ^ 1][tid * 8]);
        }

        f32x4 s[4] = {};
        __builtin_amdgcn_s_setprio(1);
#pragma unroll
        for (int j = 0; j < 4; j++)
#pragma unroll
            for (int half = 0; half < 2; half++) {
                bf16x8 kf = *(bf16x8*)((char*)&Ks[cur][0] + (j * 16 + c) * 128 +
                                       (((unsigned)(half * 64 + g * 16)) ^ swz));
                s[j] = __builtin_amdgcn_mfma_f32_16x16x32_bf16(kf, qf[half], s[j], 0, 0, 0);
            }
        __builtin_amdgcn_s_setprio(0);
        // s[j][r] = z[kv = kt+j*16+g*4+r][q], already scaled by 0.125*log2e

        if (kt + 64 > sl) {                       // partial/masked tile only (block-uniform)
#pragma unroll
            for (int j = 0; j < 4; j++) {
                int kbase = kt + j * 16 + g * 4;
#pragma unroll
                for (int r = 0; r < 4; r++)
                    if (kbase + r >= sl) s[j][r] = -14427.0f;  // ~ -10000*log2e; exp2 -> 0
            }
        }

        float tmax = -INFINITY;
#pragma unroll
        for (int j = 0; j < 4; j++)
#pragma unroll
            for (int r = 0; r < 4; r++) tmax = fmaxf(tmax, s[j][r]);
        tmax = fmaxf(tmax, __shfl_xor(tmax, 16));
        tmax = fmaxf(tmax, __shfl_xor(tmax, 32));

        float p[4][4];
        float ps = 0.f;
        bool defer = __all(tmax <= m_ + 8.f);
        float mn = defer ? m_ : fmaxf(m_, tmax);
#pragma unroll
        for (int j = 0; j < 4; j++)
#pragma unroll
            for (int r = 0; r < 4; r++) {
                p[j][r] = __builtin_amdgcn_exp2f(s[j][r] - mn);
                ps += p[j][r];
            }
        ps += __shfl_xor(ps, 16);
        ps += __shfl_xor(ps, 32);
        if (defer) {
            l_ += ps;
        } else {
            float alpha = __builtin_amdgcn_exp2f(m_ - mn);
            l_ = l_ * alpha + ps;
            m_ = mn;
            float av[4];
#pragma unroll
            for (int r = 0; r < 4; r++) av[r] = __shfl(alpha, g * 4 + r);
#pragma unroll
            for (int go = 0; go < 4; go++)
#pragma unroll
                for (int r = 0; r < 4; r++) o[go][r] *= av[r];
        }

        // write P[q=c][kv = j*16+g*4 .. +3] as one b64, XOR-swizzled (per-wave buffer)
#pragma unroll
        for (int j = 0; j < 4; j++) {
            __hip_bfloat162 lo = __float22bfloat162_rn(make_float2(p[j][0], p[j][1]));
            __hip_bfloat162 hi = __float22bfloat162_rn(make_float2(p[j][2], p[j][3]));
            uint2 u;
            u.x = *(unsigned*)&lo;
            u.y = *(unsigned*)&hi;
            *(uint2*)(Pw + c * 128 + (((unsigned)(j * 32 + g * 8)) ^ swz)) = u;
        }
        // read A-fragments: P[q=c][kv = half*32 + g*8 .. +7] (same-wave dep, hw-ordered)
        bf16x8 pf0 = *(bf16x8*)(Pw + c * 128 + (((unsigned)(g * 16)) ^ swz));
        bf16x8 pf1 = *(bf16x8*)(Pw + c * 128 + (((unsigned)(64 + g * 16)) ^ swz));

        __builtin_amdgcn_s_setprio(1);
#pragma unroll
        for (int go = 0; go < 4; go++) {
            bf16x8 vf0 = *(bf16x8*)((char*)&Vs[cur][0] + (go * 16 + c) * 128 +
                                    (((unsigned)(g * 16)) ^ swz));
            o[go] = __builtin_amdgcn_mfma_f32_16x16x32_bf16(pf0, vf0, o[go], 0, 0, 0);
            bf16x8 vf1 = *(bf16x8*)((char*)&Vs[cur][0] + (go * 16 + c) * 128 +
                                    (((unsigned)(64 + g * 16)) ^ swz));
            o[go] = __builtin_amdgcn_mfma_f32_16x16x32_bf16(pf1, vf1, o[go], 0, 0, 0);
        }
        __builtin_amdgcn_s_setprio(0);
        cur ^= 1;
    }

    // final divide: l for q = g*4+r lives at lane (g*4+r)
    float linv[4];
#pragma unroll
    for (int r = 0; r < 4; r++) linv[r] = 1.f / __shfl(l_, g * 4 + r);
#pragma unroll
    for (int go = 0; go < 4; go++)
#pragma unroll
        for (int r = 0; r < 4; r++) {
            int t = q0 + w * 16 + g * 4 + r;
            int col = h * DKK + go * 16 + c;
            ctx[((size_t)(b * TT + t)) * HH + col] = f2bf(o[go][r] * linv[r]);
        }
}

// ---------------- row LayerNorm in-place on d_out (fp32), eps=1e-12 ----------------
__global__ __launch_bounds__(256) void ln_kernel(float* __restrict__ x,
                                                 const float* __restrict__ gam,
                                                 const float* __restrict__ bet) {
    int row = blockIdx.x, tid = threadIdx.x;
    float4 v = reinterpret_cast<float4*>(x)[(size_t)row * 256 + tid];
    float s = v.x + v.y + v.z + v.w;
#pragma unroll
    for (int m = 1; m < 64; m <<= 1) s += __shfl_xor(s, m);
    __shared__ float red[4], red2[4];
    if ((tid & 63) == 0) red[tid >> 6] = s;
    __syncthreads();
    float mean = (red[0] + red[1] + red[2] + red[3]) * (1.f / 1024.f);
    float dx0 = v.x - mean, dx1 = v.y - mean, dx2 = v.z - mean, dx3 = v.w - mean;
    float ss = dx0 * dx0 + dx1 * dx1 + dx2 * dx2 + dx3 * dx3;
#pragma unroll
    for (int m = 1; m < 64; m <<= 1) ss += __shfl_xor(ss, m);
    if ((tid & 63) == 0) red2[tid >> 6] = ss;
    __syncthreads();
    float var = (red2[0] + red2[1] + red2[2] + red2[3]) * (1.f / 1024.f);
    float rs = rsqrtf(var + 1e-12f);
    int c = tid * 4;
    float4 ov;
    ov.x = dx0 * rs * gam[c + 0] + bet[c + 0];
    ov.y = dx1 * rs * gam[c + 1] + bet[c + 1];
    ov.z = dx2 * rs * gam[c + 2] + bet[c + 2];
    ov.w = dx3 * rs * gam[c + 3] + bet[c + 3];
    reinterpret_cast<float4*>(x)[(size_t)row * 256 + tid] = ov;
}

extern "C" void kernel_launch(void* const* d_in, const int* in_sizes, int n_in,
                              void* d_out, int out_size, void* d_ws, size_t ws_size,
                              hipStream_t stream) {
    const float* hid  = (const float*)d_in[0];
    const float* src  = (const float*)d_in[1];
    const int* slen   = (const int*)d_in[2];   // harness passes integers as int32
    const float* Wq  = (const float*)d_in[3];  const float* bq  = (const float*)d_in[4];
    const float* Wk  = (const float*)d_in[5];  const float* bk  = (const float*)d_in[6];
    const float* Wv  = (const float*)d_in[7];  const float* bv  = (const float*)d_in[8];
    const float* Wd  = (const float*)d_in[9];  const float* bd  = (const float*)d_in[10];
    const float* Wp1 = (const float*)d_in[11]; const float* bp1 = (const float*)d_in[12];
    const float* Wp2 = (const float*)d_in[13]; const float* bp2 = (const float*)d_in[14];
    const float* lng = (const float*)d_in[15]; const float* lnb = (const float*)d_in[16];

    // Workspace layout (bytes).
    char* ws = (char*)d_ws;
    const size_t MB = 1ull << 20;
    unsigned short* Wqt  = (unsigned short*)(ws + 0 * MB);
    unsigned short* Wkt  = (unsigned short*)(ws + 2 * MB);
    unsigned short* Wvt  = (unsigned short*)(ws + 4 * MB);
    unsigned short* Wdt  = (unsigned short*)(ws + 6 * MB);
    unsigned short* Wp1t = (unsigned short*)(ws + 8 * MB);
    unsigned short* Wp2t = (unsigned short*)(ws + 10 * MB);
    unsigned short* Kb   = (unsigned short*)(ws + 12 * MB);
    unsigned short* ctxb = (unsigned short*)(ws + 28 * MB);
    unsigned short* Vtb  = (unsigned short*)(ws + 44 * MB);
    unsigned short* Pb   = (unsigned short*)(ws + 60 * MB);
    unsigned short* Qb   = (unsigned short*)(ws + 76 * MB);
    unsigned short* Ptmp = ctxb;   // Wp1 output; dead after Pb is built, slot reused for ctx

    // all 6 weight transposes in one dispatch (64x64 tiles, coalesced)
    wtcvt6_kernel<<<dim3(16, 16, 6), dim3(32, 8), 0, stream>>>(
        Wq, Wk, Wv, Wd, Wp1, Wp2, Wqt, Wkt, Wvt, Wdt, Wp1t, Wp2t);

    dim3 gg(8, 64);  // fixed (8,64) grid; in-kernel XCD tile swizzle
    // P = mask(relu(src@Wp1+bp1)@Wp2+bp2); rows >= ceil64(sl) are dead -> SKIP
    // src/hid converted fp32->bf16 inside the staging loop (F32A) — no separate cvt pass
    gemm_kernel<1, true, true><<<gg, 256, 0, stream>>>(nullptr, src, Wp1t, bp1, Ptmp, nullptr, nullptr, slen, BB * TT, HH, HH);
    gemm_kernel<2, true, false><<<gg, 256, 0, stream>>>(Ptmp, nullptr, Wp2t, bp2, Pb, nullptr, nullptr, slen, BB * TT, HH, HH);
    // Q (pre-scaled for base-2 softmax) all rows; K,V only live rows (separate dispatches —
    // GEMM fusion regressed twice, r7/r13)
    gemm_kernel<6, false, true><<<gg, 256, 0, stream>>>(nullptr, hid, Wqt, bq, Qb, nullptr, nullptr, slen, BB * TT, HH, HH);
    gemm_kernel<3, true, false><<<gg, 256, 0, stream>>>(Pb, nullptr, Wkt, bk, Kb, nullptr, nullptr, slen, BB * TT, HH, HH);
    gemm_kernel<4, true, false><<<gg, 256, 0, stream>>>(Pb, nullptr, Wvt, bv, Vtb, nullptr, nullptr, slen, BB * TT, HH, HH);
    // attention -> ctx (B,T,H) bf16 (2D grid = per-CU batch mix; dbuf, 1 barrier/tile)
    attn_kernel<<<dim3(TT / 128, NHH, BB), 512, 0, stream>>>(Qb, Kb, Vtb, slen, ctxb);
    // x = ctx@Wd + bd + hidden -> d_out fp32
    gemm_kernel<5, false, false><<<gg, 256, 0, stream>>>(ctxb, nullptr, Wdt, bd, nullptr, (float*)d_out, hid, slen, BB * TT, HH, HH);
    // LayerNorm in place
    ln_kernel<<<BB * TT, 256, 0, stream>>>((float*)d_out, lng, lnb);
}

// Round 16
// 248.357 us; speedup vs baseline: 1.0072x; 1.0072x over previous
//
#include <hip/hip_runtime.h>
#include <hip/hip_bf16.h>

// Problem dims (fixed by the reference)
#define BB 4
#define TT 2048
#define HH 1024
#define NHH 16
#define DKK 64
// M = BB*TT = 8192, K = N = HH = 1024

typedef __attribute__((ext_vector_type(8))) short bf16x8;
typedef __attribute__((ext_vector_type(4))) float f32x4;

__device__ __forceinline__ unsigned short f2bf(float f) {
    union { float f; unsigned u; } v; v.f = f;
    unsigned r = v.u + 0x7fffu + ((v.u >> 16) & 1u);  // RNE
    return (unsigned short)(r >> 16);
}

__device__ __forceinline__ float bf2f(unsigned short u) {
    union { unsigned u; float f; } v; v.u = ((unsigned)u) << 16;
    return v.f;
}

__device__ __forceinline__ bf16x8 cvt8(const float* __restrict__ p) {
    float4 a = *(const float4*)p;
    float4 b = *(const float4*)(p + 4);
    bf16x8 r;
    r[0] = (short)f2bf(a.x); r[1] = (short)f2bf(a.y);
    r[2] = (short)f2bf(a.z); r[3] = (short)f2bf(a.w);
    r[4] = (short)f2bf(b.x); r[5] = (short)f2bf(b.y);
    r[6] = (short)f2bf(b.z); r[7] = (short)f2bf(b.w);
    return r;
}

// async global->LDS, 16B per lane; LDS dest must be linear in lane order
__device__ __forceinline__ void gload_lds16(const unsigned short* g, unsigned short* l) {
    __builtin_amdgcn_global_load_lds(
        (const __attribute__((address_space(1))) unsigned int*)g,
        (__attribute__((address_space(3))) unsigned int*)l, 16, 0, 0);
}

// ---------------- weight transpose + convert, all 6 weights, 64x64 tiles, coalesced ----------------
__global__ __launch_bounds__(256) void wtcvt6_kernel(
    const float* __restrict__ W0, const float* __restrict__ W1, const float* __restrict__ W2,
    const float* __restrict__ W3, const float* __restrict__ W4, const float* __restrict__ W5,
    unsigned short* __restrict__ T0, unsigned short* __restrict__ T1, unsigned short* __restrict__ T2,
    unsigned short* __restrict__ T3, unsigned short* __restrict__ T4, unsigned short* __restrict__ T5) {
    const float* W; unsigned short* Wt;
    switch (blockIdx.z) {
        case 0: W = W0; Wt = T0; break;
        case 1: W = W1; Wt = T1; break;
        case 2: W = W2; Wt = T2; break;
        case 3: W = W3; Wt = T3; break;
        case 4: W = W4; Wt = T4; break;
        default: W = W5; Wt = T5; break;
    }
    __shared__ float t[64][65];
    int bx = blockIdx.x * 64, by = blockIdx.y * 64;   // bx: n-range, by: k-range
    int tx = threadIdx.x, ty = threadIdx.y;           // block (32,8)
#pragma unroll
    for (int i = 0; i < 8; i++) {
        int kk = ty + 8 * i;
        float2 v = *(const float2*)&W[(size_t)(by + kk) * HH + bx + 2 * tx];
        t[kk][2 * tx] = v.x;
        t[kk][2 * tx + 1] = v.y;
    }
    __syncthreads();
#pragma unroll
    for (int i = 0; i < 8; i++) {
        int nn = ty + 8 * i;
        unsigned u = (unsigned)f2bf(t[2 * tx][nn]) | ((unsigned)f2bf(t[2 * tx + 1][nn]) << 16);
        *(unsigned*)&Wt[(size_t)(bx + nn) * HH + by + 2 * tx] = u;  // Wt[n][k] = W[k][n]
    }
}

// ---------------- MFMA GEMM (m97 structure): 128x128 tile, BK=64, global_load_lds w=16 ----------------
// Grid FIXED (8,64), in-kernel XCD tile swizzle. F32A: A fp32, reg-staged + converted.
// EPI: 1=relu->bf16  2=source-mask->bf16  3=head-split (K)  6=head-split * 0.125*log2e (Q)
//      4=transposed-head (V), operands swapped -> coalesced Vt store
//      5=+resid, x stored as BF16 (LN reads bf16 -> 32MB less HBM traffic)
template <int EPI, bool SKIP, bool F32A>
__global__ __launch_bounds__(256) void gemm_kernel(
    const unsigned short* __restrict__ A16, const float* __restrict__ A32,
    const unsigned short* __restrict__ Bt,
    const float* __restrict__ bias, unsigned short* __restrict__ Cb,
    float* __restrict__ Cf, const float* __restrict__ resid,
    const int* __restrict__ slen, int M, int N, int K) {
    __shared__ unsigned short As[128 * 64];   // [row][k] linear
    __shared__ unsigned short Bs[128 * 64];
    // XCD swizzle (bijective for 8x64 grid): xcd = flat&7 owns rows {xcd, xcd+8, ...}
    int flat = blockIdx.y * 8 + blockIdx.x;
    int xcd = flat & 7, idx = flat >> 3;
    int bx = (idx & 7) * 128;
    int by = (xcd + ((idx >> 3) << 3)) * 128;
    if constexpr (SKIP) {
        int slb = slen[by >> 11];
        int ktend = ((slb + 63) >> 6) << 6;
        if (ktend == 0) ktend = 64;           // attention still reads tile 0 (uniform-softmax case)
        if ((by & (TT - 1)) >= ktend) return; // whole 128-row tile dead (2048 % 128 == 0)
    }
    int tid = threadIdx.x, lane = tid & 63, w = tid >> 6;
    int wr = (w >> 1) * 64, wc = (w & 1) * 64;     // wave's 64x64 output quadrant

    f32x4 acc[4][4] = {};
    for (int k0 = 0; k0 < K; k0 += 64) {
        __syncthreads();
#pragma unroll
        for (int c = 0; c < 4; c++) {
            int idx2 = c * 256 + tid;
            int r = idx2 >> 3, col = (idx2 & 7) * 8;
            if constexpr (F32A) {
                *(bf16x8*)&As[idx2 * 8] = cvt8(&A32[(size_t)(by + r) * K + k0 + col]);
            } else {
                gload_lds16(&A16[(size_t)(by + r) * K + k0 + col], &As[idx2 * 8]);
            }
            gload_lds16(&Bt[(size_t)(bx + r) * K + k0 + col], &Bs[idx2 * 8]);
        }
        __syncthreads();  // drains vmcnt(0) + lgkmcnt
#pragma unroll
        for (int kk = 0; kk < 2; kk++) {
            bf16x8 a[4], b[4];
#pragma unroll
            for (int i = 0; i < 4; i++)
                a[i] = *(bf16x8*)&As[(wr + i * 16 + (lane & 15)) * 64 + kk * 32 + (lane >> 4) * 8];
#pragma unroll
            for (int j = 0; j < 4; j++)
                b[j] = *(bf16x8*)&Bs[(wc + j * 16 + (lane & 15)) * 64 + kk * 32 + (lane >> 4) * 8];
#pragma unroll
            for (int i = 0; i < 4; i++)
#pragma unroll
                for (int j = 0; j < 4; j++) {
                    if constexpr (EPI == 4)
                        acc[i][j] = __builtin_amdgcn_mfma_f32_16x16x32_bf16(b[j], a[i], acc[i][j], 0, 0, 0);
                    else
                        acc[i][j] = __builtin_amdgcn_mfma_f32_16x16x32_bf16(a[i], b[j], acc[i][j], 0, 0, 0);
                }
        }
    }

    int sl = 0;
    if constexpr (EPI == 2) sl = slen[by >> 11];  // 128-row tile never crosses a batch
#pragma unroll
    for (int i = 0; i < 4; i++)
#pragma unroll
        for (int j = 0; j < 4; j++)
#pragma unroll
            for (int r = 0; r < 4; r++) {
                if constexpr (EPI == 4) {
                    // swapped D: row-dim = n (from b[j]), col-dim = m (from a[i])
                    int nrow = bx + wc + j * 16 + (lane >> 4) * 4 + r;
                    int mcol = by + wr + i * 16 + (lane & 15);
                    float v = acc[i][j][r] + bias[nrow];
                    int b = mcol >> 11, t = mcol & (TT - 1), h = nrow >> 6, d = nrow & 63;
                    Cb[((size_t)((b * NHH + h) * DKK + d)) * TT + t] = f2bf(v);
                } else {
                    int row = by + wr + i * 16 + (lane >> 4) * 4 + r;
                    int col = bx + wc + j * 16 + (lane & 15);
                    float v = acc[i][j][r] + bias[col];
                    if constexpr (EPI == 1) v = fmaxf(v, 0.f);
                    if constexpr (EPI == 2) { int t = row & (TT - 1); if (t >= sl) v = 0.f; }
                    if constexpr (EPI == 6) v *= 0.18033688f;   // 0.125 * log2(e)
                    if constexpr (EPI == 1 || EPI == 2) {
                        Cb[(size_t)row * N + col] = f2bf(v);
                    } else if constexpr (EPI == 3 || EPI == 6) {
                        int b = row >> 11, t = row & (TT - 1), h = col >> 6, d = col & 63;
                        Cb[((size_t)((b * NHH + h) * TT + t)) * DKK + d] = f2bf(v);
                    } else if constexpr (EPI == 5) {
                        Cb[(size_t)row * N + col] = f2bf(v + resid[(size_t)row * N + col]);
                    }
                }
            }
}

// ---------------- flash attention: block = (b, h, 128 q-rows), 8 waves x 16 q-rows ----------------
// r15 config (62us): 2D grid, KVBLK=64, dbuf w/ ONE barrier per tile, swapped QK^T, base-2
// softmax, T13 defer-max, full-tile mask skip. This round: depth-4 TREE reductions for tmax/ps
// (was depth-15/16 serial chains on the critical VALU path).
__global__ __launch_bounds__(512, 6) void attn_kernel(
    const unsigned short* __restrict__ Q, const unsigned short* __restrict__ K,
    const unsigned short* __restrict__ Vt, const int* __restrict__ slen,
    unsigned short* __restrict__ ctx) {
    __shared__ unsigned short Ks[2][64 * 64];     // [kv][dk], XOR-swizzled content
    __shared__ unsigned short Vs[2][64 * 64];     // [dk][kv], XOR-swizzled content
    __shared__ unsigned short Pl[8][16 * 64];     // per-wave P [q][kv], XOR-swizzled
    int tid = threadIdx.x, lane = tid & 63, w = tid >> 6;
    int c = lane & 15, g = lane >> 4;
    int b = blockIdx.z, h = blockIdx.y, q0 = blockIdx.x * 128;
    size_t bhs = (size_t)(b * NHH + h);
    int sl = slen[b];
    int ktend = ((sl + 63) >> 6) << 6;
    if (ktend == 0) ktend = 64;                   // all-masked: one tile, uniform softmax -> bv

    bf16x8 qf[2];                                 // B-operand: Q[q = w*16+c][dk]
    int qrow = q0 + w * 16 + c;
#pragma unroll
    for (int half = 0; half < 2; half++)
        qf[half] = *(const bf16x8*)&Q[(bhs * TT + qrow) * DKK + half * 32 + g * 8];

    char* Pw = (char*)&Pl[w][0];
    unsigned swz = (unsigned)((c & 7) << 4);

    // staging coords: thread stages chunk (r = tid>>3, slot = tid&7) of both K and V;
    // source slot pre-swizzled so LDS[r][s] = G[r][s ^ (r&7)]
    int sr = tid >> 3, ss = tid & 7;
    int scol = (ss ^ (sr & 7)) * 8;

    // prologue: issue tile-0 loads into buffer 0 (drained by the loop's first barrier)
    gload_lds16(&K[(bhs * TT + sr) * DKK + scol], &Ks[0][tid * 8]);
    gload_lds16(&Vt[(bhs * DKK + sr) * TT + scol], &Vs[0][tid * 8]);
    int cur = 0;

    float m_ = -INFINITY, l_ = 0.f;               // state for q-row (w*16 + c), log2 domain
    f32x4 o[4] = {};                              // O[q = g*4+r][d = go*16+c]

    for (int kt = 0; kt < ktend; kt += 64) {
        __syncthreads();   // drains vmcnt -> buf[cur] ready; all waves done reading buf[cur^1]
        if (kt + 64 < ktend) {                    // prefetch next tile into the other buffer
            gload_lds16(&K[(bhs * TT + kt + 64 + sr) * DKK + scol], &Ks[cur ^ 1][tid * 8]);
            gload_lds16(&Vt[(bhs * DKK + sr) * TT + kt + 64 + scol], &Vs[cur ^ 1][tid * 8]);
        }

        f32x4 s[4] = {};
        __builtin_amdgcn_s_setprio(1);
#pragma unroll
        for (int j = 0; j < 4; j++)
#pragma unroll
            for (int half = 0; half < 2; half++) {
                bf16x8 kf = *(bf16x8*)((char*)&Ks[cur][0] + (j * 16 + c) * 128 +
                                       (((unsigned)(half * 64 + g * 16)) ^ swz));
                s[j] = __builtin_amdgcn_mfma_f32_16x16x32_bf16(kf, qf[half], s[j], 0, 0, 0);
            }
        __builtin_amdgcn_s_setprio(0);
        // s[j][r] = z[kv = kt+j*16+g*4+r][q], already scaled by 0.125*log2e

        if (kt + 64 > sl) {                       // partial/masked tile only (block-uniform)
#pragma unroll
            for (int j = 0; j < 4; j++) {
                int kbase = kt + j * 16 + g * 4;
#pragma unroll
                for (int r = 0; r < 4; r++)
                    if (kbase + r >= sl) s[j][r] = -14427.0f;  // ~ -10000*log2e; exp2 -> 0
            }
        }

        // depth-4 tree max (exact; was depth-15 serial chain)
        float mj[4];
#pragma unroll
        for (int j = 0; j < 4; j++)
            mj[j] = fmaxf(fmaxf(s[j][0], s[j][1]), fmaxf(s[j][2], s[j][3]));
        float tmax = fmaxf(fmaxf(mj[0], mj[1]), fmaxf(mj[2], mj[3]));
        tmax = fmaxf(tmax, __shfl_xor(tmax, 16));
        tmax = fmaxf(tmax, __shfl_xor(tmax, 32));

        float p[4][4];
        bool defer = __all(tmax <= m_ + 8.f);
        float mn = defer ? m_ : fmaxf(m_, tmax);
        float psj[4];
#pragma unroll
        for (int j = 0; j < 4; j++) {
            p[j][0] = __builtin_amdgcn_exp2f(s[j][0] - mn);
            p[j][1] = __builtin_amdgcn_exp2f(s[j][1] - mn);
            p[j][2] = __builtin_amdgcn_exp2f(s[j][2] - mn);
            p[j][3] = __builtin_amdgcn_exp2f(s[j][3] - mn);
            psj[j] = (p[j][0] + p[j][1]) + (p[j][2] + p[j][3]);
        }
        float ps = (psj[0] + psj[1]) + (psj[2] + psj[3]);
        ps += __shfl_xor(ps, 16);
        ps += __shfl_xor(ps, 32);
        if (defer) {
            l_ += ps;
        } else {
            float alpha = __builtin_amdgcn_exp2f(m_ - mn);
            l_ = l_ * alpha + ps;
            m_ = mn;
            float av[4];
#pragma unroll
            for (int r = 0; r < 4; r++) av[r] = __shfl(alpha, g * 4 + r);
#pragma unroll
            for (int go = 0; go < 4; go++)
#pragma unroll
                for (int r = 0; r < 4; r++) o[go][r] *= av[r];
        }

        // write P[q=c][kv = j*16+g*4 .. +3] as one b64, XOR-swizzled (per-wave buffer)
#pragma unroll
        for (int j = 0; j < 4; j++) {
            __hip_bfloat162 lo = __float22bfloat162_rn(make_float2(p[j][0], p[j][1]));
            __hip_bfloat162 hi = __float22bfloat162_rn(make_float2(p[j][2], p[j][3]));
            uint2 u;
            u.x = *(unsigned*)&lo;
            u.y = *(unsigned*)&hi;
            *(uint2*)(Pw + c * 128 + (((unsigned)(j * 32 + g * 8)) ^ swz)) = u;
        }
        // read A-fragments: P[q=c][kv = half*32 + g*8 .. +7] (same-wave dep, hw-ordered)
        bf16x8 pf0 = *(bf16x8*)(Pw + c * 128 + (((unsigned)(g * 16)) ^ swz));
        bf16x8 pf1 = *(bf16x8*)(Pw + c * 128 + (((unsigned)(64 + g * 16)) ^ swz));

        __builtin_amdgcn_s_setprio(1);
#pragma unroll
        for (int go = 0; go < 4; go++) {
            bf16x8 vf0 = *(bf16x8*)((char*)&Vs[cur][0] + (go * 16 + c) * 128 +
                                    (((unsigned)(g * 16)) ^ swz));
            o[go] = __builtin_amdgcn_mfma_f32_16x16x32_bf16(pf0, vf0, o[go], 0, 0, 0);
            bf16x8 vf1 = *(bf16x8*)((char*)&Vs[cur][0] + (go * 16 + c) * 128 +
                                    (((unsigned)(64 + g * 16)) ^ swz));
            o[go] = __builtin_amdgcn_mfma_f32_16x16x32_bf16(pf1, vf1, o[go], 0, 0, 0);
        }
        __builtin_amdgcn_s_setprio(0);
        cur ^= 1;
    }

    // final divide: l for q = g*4+r lives at lane (g*4+r)
    float linv[4];
#pragma unroll
    for (int r = 0; r < 4; r++) linv[r] = 1.f / __shfl(l_, g * 4 + r);
#pragma unroll
    for (int go = 0; go < 4; go++)
#pragma unroll
        for (int r = 0; r < 4; r++) {
            int t = q0 + w * 16 + g * 4 + r;
            int col = h * DKK + go * 16 + c;
            ctx[((size_t)(b * TT + t)) * HH + col] = f2bf(o[go][r] * linv[r]);
        }
}

// ---------------- row LayerNorm: reads x (bf16), writes d_out (fp32), eps=1e-12 ----------------
__global__ __launch_bounds__(256) void ln_kernel(const unsigned short* __restrict__ xb,
                                                 float* __restrict__ out,
                                                 const float* __restrict__ gam,
                                                 const float* __restrict__ bet) {
    int row = blockIdx.x, tid = threadIdx.x;
    ushort4 uv = reinterpret_cast<const ushort4*>(xb)[(size_t)row * 256 + tid];
    float x0 = bf2f(uv.x), x1 = bf2f(uv.y), x2 = bf2f(uv.z), x3 = bf2f(uv.w);
    float s = (x0 + x1) + (x2 + x3);
#pragma unroll
    for (int m = 1; m < 64; m <<= 1) s += __shfl_xor(s, m);
    __shared__ float red[4], red2[4];
    if ((tid & 63) == 0) red[tid >> 6] = s;
    __syncthreads();
    float mean = (red[0] + red[1] + red[2] + red[3]) * (1.f / 1024.f);
    float dx0 = x0 - mean, dx1 = x1 - mean, dx2 = x2 - mean, dx3 = x3 - mean;
    float ss = (dx0 * dx0 + dx1 * dx1) + (dx2 * dx2 + dx3 * dx3);
#pragma unroll
    for (int m = 1; m < 64; m <<= 1) ss += __shfl_xor(ss, m);
    if ((tid & 63) == 0) red2[tid >> 6] = ss;
    __syncthreads();
    float var = (red2[0] + red2[1] + red2[2] + red2[3]) * (1.f / 1024.f);
    float rs = rsqrtf(var + 1e-12f);
    int c = tid * 4;
    float4 ov;
    ov.x = dx0 * rs * gam[c + 0] + bet[c + 0];
    ov.y = dx1 * rs * gam[c + 1] + bet[c + 1];
    ov.z = dx2 * rs * gam[c + 2] + bet[c + 2];
    ov.w = dx3 * rs * gam[c + 3] + bet[c + 3];
    reinterpret_cast<float4*>(out)[(size_t)row * 256 + tid] = ov;
}

extern "C" void kernel_launch(void* const* d_in, const int* in_sizes, int n_in,
                              void* d_out, int out_size, void* d_ws, size_t ws_size,
                              hipStream_t stream) {
    const float* hid  = (const float*)d_in[0];
    const float* src  = (const float*)d_in[1];
    const int* slen   = (const int*)d_in[2];   // harness passes integers as int32
    const float* Wq  = (const float*)d_in[3];  const float* bq  = (const float*)d_in[4];
    const float* Wk  = (const float*)d_in[5];  const float* bk  = (const float*)d_in[6];
    const float* Wv  = (const float*)d_in[7];  const float* bv  = (const float*)d_in[8];
    const float* Wd  = (const float*)d_in[9];  const float* bd  = (const float*)d_in[10];
    const float* Wp1 = (const float*)d_in[11]; const float* bp1 = (const float*)d_in[12];
    const float* Wp2 = (const float*)d_in[13]; const float* bp2 = (const float*)d_in[14];
    const float* lng = (const float*)d_in[15]; const float* lnb = (const float*)d_in[16];

    // Workspace layout (bytes).
    char* ws = (char*)d_ws;
    const size_t MB = 1ull << 20;
    unsigned short* Wqt  = (unsigned short*)(ws + 0 * MB);
    unsigned short* Wkt  = (unsigned short*)(ws + 2 * MB);
    unsigned short* Wvt  = (unsigned short*)(ws + 4 * MB);
    unsigned short* Wdt  = (unsigned short*)(ws + 6 * MB);
    unsigned short* Wp1t = (unsigned short*)(ws + 8 * MB);
    unsigned short* Wp2t = (unsigned short*)(ws + 10 * MB);
    unsigned short* Kb   = (unsigned short*)(ws + 12 * MB);
    unsigned short* ctxb = (unsigned short*)(ws + 28 * MB);
    unsigned short* Vtb  = (unsigned short*)(ws + 44 * MB);
    unsigned short* Pb   = (unsigned short*)(ws + 60 * MB);
    unsigned short* Qb   = (unsigned short*)(ws + 76 * MB);
    unsigned short* Ptmp = ctxb;   // Wp1 output; dead after Pb is built, slot reused for ctx
    unsigned short* xb   = Kb;     // x = attn_out + hidden (bf16); Kb dead after attention

    // all 6 weight transposes in one dispatch (64x64 tiles, coalesced)
    wtcvt6_kernel<<<dim3(16, 16, 6), dim3(32, 8), 0, stream>>>(
        Wq, Wk, Wv, Wd, Wp1, Wp2, Wqt, Wkt, Wvt, Wdt, Wp1t, Wp2t);

    dim3 gg(8, 64);  // fixed (8,64) grid; in-kernel XCD tile swizzle
    // P = mask(relu(src@Wp1+bp1)@Wp2+bp2); rows >= ceil64(sl) are dead -> SKIP
    // src/hid converted fp32->bf16 inside the staging loop (F32A) — no separate cvt pass
    gemm_kernel<1, true, true><<<gg, 256, 0, stream>>>(nullptr, src, Wp1t, bp1, Ptmp, nullptr, nullptr, slen, BB * TT, HH, HH);
    gemm_kernel<2, true, false><<<gg, 256, 0, stream>>>(Ptmp, nullptr, Wp2t, bp2, Pb, nullptr, nullptr, slen, BB * TT, HH, HH);
    // Q (pre-scaled for base-2 softmax) all rows; K,V only live rows (separate dispatches —
    // GEMM fusion regressed twice, r7/r13)
    gemm_kernel<6, false, true><<<gg, 256, 0, stream>>>(nullptr, hid, Wqt, bq, Qb, nullptr, nullptr, slen, BB * TT, HH, HH);
    gemm_kernel<3, true, false><<<gg, 256, 0, stream>>>(Pb, nullptr, Wkt, bk, Kb, nullptr, nullptr, slen, BB * TT, HH, HH);
    gemm_kernel<4, true, false><<<gg, 256, 0, stream>>>(Pb, nullptr, Wvt, bv, Vtb, nullptr, nullptr, slen, BB * TT, HH, HH);
    // attention -> ctx (B,T,H) bf16
    attn_kernel<<<dim3(TT / 128, NHH, BB), 512, 0, stream>>>(Qb, Kb, Vtb, slen, ctxb);
    // x = ctx@Wd + bd + hidden -> xb (bf16; Kb slot now dead)
    gemm_kernel<5, false, false><<<gg, 256, 0, stream>>>(ctxb, nullptr, Wdt, bd, xb, nullptr, hid, slen, BB * TT, HH, HH);
    // LayerNorm: bf16 x -> fp32 d_out
    ln_kernel<<<BB * TT, 256, 0, stream>>>(xb, (float*)d_out, lng, lnb);
}

// Round 17
// 247.627 us; speedup vs baseline: 1.0101x; 1.0029x over previous
//
#include <hip/hip_runtime.h>
#include <hip/hip_bf16.h>

// Problem dims (fixed by the reference)
#define BB 4
#define TT 2048
#define HH 1024
#define NHH 16
#define DKK 64
// M = BB*TT = 8192, K = N = HH = 1024

typedef __attribute__((ext_vector_type(8))) short bf16x8;
typedef __attribute__((ext_vector_type(4))) float f32x4;

__device__ __forceinline__ unsigned short f2bf(float f) {
    union { float f; unsigned u; } v; v.f = f;
    unsigned r = v.u + 0x7fffu + ((v.u >> 16) & 1u);  // RNE
    return (unsigned short)(r >> 16);
}

__device__ __forceinline__ float bf2f(unsigned short u) {
    union { unsigned u; float f; } v; v.u = ((unsigned)u) << 16;
    return v.f;
}

__device__ __forceinline__ bf16x8 cvt8(const float* __restrict__ p) {
    float4 a = *(const float4*)p;
    float4 b = *(const float4*)(p + 4);
    bf16x8 r;
    r[0] = (short)f2bf(a.x); r[1] = (short)f2bf(a.y);
    r[2] = (short)f2bf(a.z); r[3] = (short)f2bf(a.w);
    r[4] = (short)f2bf(b.x); r[5] = (short)f2bf(b.y);
    r[6] = (short)f2bf(b.z); r[7] = (short)f2bf(b.w);
    return r;
}

// async global->LDS, 16B per lane; LDS dest must be linear in lane order
__device__ __forceinline__ void gload_lds16(const unsigned short* g, unsigned short* l) {
    __builtin_amdgcn_global_load_lds(
        (const __attribute__((address_space(1))) unsigned int*)g,
        (__attribute__((address_space(3))) unsigned int*)l, 16, 0, 0);
}

// ---------------- weight transpose + convert, all 6 weights, 64x64 tiles, coalesced ----------------
__global__ __launch_bounds__(256) void wtcvt6_kernel(
    const float* __restrict__ W0, const float* __restrict__ W1, const float* __restrict__ W2,
    const float* __restrict__ W3, const float* __restrict__ W4, const float* __restrict__ W5,
    unsigned short* __restrict__ T0, unsigned short* __restrict__ T1, unsigned short* __restrict__ T2,
    unsigned short* __restrict__ T3, unsigned short* __restrict__ T4, unsigned short* __restrict__ T5) {
    const float* W; unsigned short* Wt;
    switch (blockIdx.z) {
        case 0: W = W0; Wt = T0; break;
        case 1: W = W1; Wt = T1; break;
        case 2: W = W2; Wt = T2; break;
        case 3: W = W3; Wt = T3; break;
        case 4: W = W4; Wt = T4; break;
        default: W = W5; Wt = T5; break;
    }
    __shared__ float t[64][65];
    int bx = blockIdx.x * 64, by = blockIdx.y * 64;   // bx: n-range, by: k-range
    int tx = threadIdx.x, ty = threadIdx.y;           // block (32,8)
#pragma unroll
    for (int i = 0; i < 8; i++) {
        int kk = ty + 8 * i;
        float2 v = *(const float2*)&W[(size_t)(by + kk) * HH + bx + 2 * tx];
        t[kk][2 * tx] = v.x;
        t[kk][2 * tx + 1] = v.y;
    }
    __syncthreads();
#pragma unroll
    for (int i = 0; i < 8; i++) {
        int nn = ty + 8 * i;
        unsigned u = (unsigned)f2bf(t[2 * tx][nn]) | ((unsigned)f2bf(t[2 * tx + 1][nn]) << 16);
        *(unsigned*)&Wt[(size_t)(bx + nn) * HH + by + 2 * tx] = u;  // Wt[n][k] = W[k][n]
    }
}

// ---------------- MFMA GEMM (m97 structure): 128x128 tile, BK=64, global_load_lds w=16 ----------------
// Grid FIXED (8,64), in-kernel XCD tile swizzle. F32A: A fp32, reg-staged + converted.
// EPI: 1=relu->bf16  2=source-mask->bf16  3=head-split (K)  6=head-split * 0.125*log2e (Q)
//      4=transposed-head (V), operands swapped -> coalesced Vt store
//      5=+resid, x stored as BF16 (LN reads bf16 -> 32MB less HBM traffic)
template <int EPI, bool SKIP, bool F32A>
__global__ __launch_bounds__(256) void gemm_kernel(
    const unsigned short* __restrict__ A16, const float* __restrict__ A32,
    const unsigned short* __restrict__ Bt,
    const float* __restrict__ bias, unsigned short* __restrict__ Cb,
    float* __restrict__ Cf, const float* __restrict__ resid,
    const int* __restrict__ slen, int M, int N, int K) {
    __shared__ unsigned short As[128 * 64];   // [row][k] linear
    __shared__ unsigned short Bs[128 * 64];
    // XCD swizzle (bijective for 8x64 grid): xcd = flat&7 owns rows {xcd, xcd+8, ...}
    int flat = blockIdx.y * 8 + blockIdx.x;
    int xcd = flat & 7, idx = flat >> 3;
    int bx = (idx & 7) * 128;
    int by = (xcd + ((idx >> 3) << 3)) * 128;
    if constexpr (SKIP) {
        int slb = slen[by >> 11];
        int ktend = ((slb + 63) >> 6) << 6;
        if (ktend == 0) ktend = 64;           // attention still reads tile 0 (uniform-softmax case)
        if ((by & (TT - 1)) >= ktend) return; // whole 128-row tile dead (2048 % 128 == 0)
    }
    int tid = threadIdx.x, lane = tid & 63, w = tid >> 6;
    int wr = (w >> 1) * 64, wc = (w & 1) * 64;     // wave's 64x64 output quadrant

    f32x4 acc[4][4] = {};
    for (int k0 = 0; k0 < K; k0 += 64) {
        __syncthreads();
#pragma unroll
        for (int c = 0; c < 4; c++) {
            int idx2 = c * 256 + tid;
            int r = idx2 >> 3, col = (idx2 & 7) * 8;
            if constexpr (F32A) {
                *(bf16x8*)&As[idx2 * 8] = cvt8(&A32[(size_t)(by + r) * K + k0 + col]);
            } else {
                gload_lds16(&A16[(size_t)(by + r) * K + k0 + col], &As[idx2 * 8]);
            }
            gload_lds16(&Bt[(size_t)(bx + r) * K + k0 + col], &Bs[idx2 * 8]);
        }
        __syncthreads();  // drains vmcnt(0) + lgkmcnt
#pragma unroll
        for (int kk = 0; kk < 2; kk++) {
            bf16x8 a[4], b[4];
#pragma unroll
            for (int i = 0; i < 4; i++)
                a[i] = *(bf16x8*)&As[(wr + i * 16 + (lane & 15)) * 64 + kk * 32 + (lane >> 4) * 8];
#pragma unroll
            for (int j = 0; j < 4; j++)
                b[j] = *(bf16x8*)&Bs[(wc + j * 16 + (lane & 15)) * 64 + kk * 32 + (lane >> 4) * 8];
#pragma unroll
            for (int i = 0; i < 4; i++)
#pragma unroll
                for (int j = 0; j < 4; j++) {
                    if constexpr (EPI == 4)
                        acc[i][j] = __builtin_amdgcn_mfma_f32_16x16x32_bf16(b[j], a[i], acc[i][j], 0, 0, 0);
                    else
                        acc[i][j] = __builtin_amdgcn_mfma_f32_16x16x32_bf16(a[i], b[j], acc[i][j], 0, 0, 0);
                }
        }
    }

    int sl = 0;
    if constexpr (EPI == 2) sl = slen[by >> 11];  // 128-row tile never crosses a batch
#pragma unroll
    for (int i = 0; i < 4; i++)
#pragma unroll
        for (int j = 0; j < 4; j++)
#pragma unroll
            for (int r = 0; r < 4; r++) {
                if constexpr (EPI == 4) {
                    // swapped D: row-dim = n (from b[j]), col-dim = m (from a[i])
                    int nrow = bx + wc + j * 16 + (lane >> 4) * 4 + r;
                    int mcol = by + wr + i * 16 + (lane & 15);
                    float v = acc[i][j][r] + bias[nrow];
                    int b = mcol >> 11, t = mcol & (TT - 1), h = nrow >> 6, d = nrow & 63;
                    Cb[((size_t)((b * NHH + h) * DKK + d)) * TT + t] = f2bf(v);
                } else {
                    int row = by + wr + i * 16 + (lane >> 4) * 4 + r;
                    int col = bx + wc + j * 16 + (lane & 15);
                    float v = acc[i][j][r] + bias[col];
                    if constexpr (EPI == 1) v = fmaxf(v, 0.f);
                    if constexpr (EPI == 2) { int t = row & (TT - 1); if (t >= sl) v = 0.f; }
                    if constexpr (EPI == 6) v *= 0.18033688f;   // 0.125 * log2(e)
                    if constexpr (EPI == 1 || EPI == 2) {
                        Cb[(size_t)row * N + col] = f2bf(v);
                    } else if constexpr (EPI == 3 || EPI == 6) {
                        int b = row >> 11, t = row & (TT - 1), h = col >> 6, d = col & 63;
                        Cb[((size_t)((b * NHH + h) * TT + t)) * DKK + d] = f2bf(v);
                    } else if constexpr (EPI == 5) {
                        Cb[(size_t)row * N + col] = f2bf(v + resid[(size_t)row * N + col]);
                    }
                }
            }
}

// ---------------- flash attention: block = (b, h, 128 q-rows), 8 waves x 16 q-rows ----------------
// r15 config exactly (measured 61.9us — best attn): 2D grid, KVBLK=64, dbuf w/ ONE barrier per
// tile, swapped QK^T, base-2 softmax, SERIAL-chain reductions (tree form measured +1.2us, r16),
// T13 defer-max, full-tile mask skip.
__global__ __launch_bounds__(512, 6) void attn_kernel(
    const unsigned short* __restrict__ Q, const unsigned short* __restrict__ K,
    const unsigned short* __restrict__ Vt, const int* __restrict__ slen,
    unsigned short* __restrict__ ctx) {
    __shared__ unsigned short Ks[2][64 * 64];     // [kv][dk], XOR-swizzled content
    __shared__ unsigned short Vs[2][64 * 64];     // [dk][kv], XOR-swizzled content
    __shared__ unsigned short Pl[8][16 * 64];     // per-wave P [q][kv], XOR-swizzled
    int tid = threadIdx.x, lane = tid & 63, w = tid >> 6;
    int c = lane & 15, g = lane >> 4;
    int b = blockIdx.z, h = blockIdx.y, q0 = blockIdx.x * 128;
    size_t bhs = (size_t)(b * NHH + h);
    int sl = slen[b];
    int ktend = ((sl + 63) >> 6) << 6;
    if (ktend == 0) ktend = 64;                   // all-masked: one tile, uniform softmax -> bv

    bf16x8 qf[2];                                 // B-operand: Q[q = w*16+c][dk]
    int qrow = q0 + w * 16 + c;
#pragma unroll
    for (int half = 0; half < 2; half++)
        qf[half] = *(const bf16x8*)&Q[(bhs * TT + qrow) * DKK + half * 32 + g * 8];

    char* Pw = (char*)&Pl[w][0];
    unsigned swz = (unsigned)((c & 7) << 4);

    // staging coords: thread stages chunk (r = tid>>3, slot = tid&7) of both K and V;
    // source slot pre-swizzled so LDS[r][s] = G[r][s ^ (r&7)]
    int sr = tid >> 3, ss = tid & 7;
    int scol = (ss ^ (sr & 7)) * 8;

    // prologue: issue tile-0 loads into buffer 0 (drained by the loop's first barrier)
    gload_lds16(&K[(bhs * TT + sr) * DKK + scol], &Ks[0][tid * 8]);
    gload_lds16(&Vt[(bhs * DKK + sr) * TT + scol], &Vs[0][tid * 8]);
    int cur = 0;

    float m_ = -INFINITY, l_ = 0.f;               // state for q-row (w*16 + c), log2 domain
    f32x4 o[4] = {};                              // O[q = g*4+r][d = go*16+c]

    for (int kt = 0; kt < ktend; kt += 64) {
        __syncthreads();   // drains vmcnt -> buf[cur] ready; all waves done reading buf[cur^1]
        if (kt + 64 < ktend) {                    // prefetch next tile into the other buffer
            gload_lds16(&K[(bhs * TT + kt + 64 + sr) * DKK + scol], &Ks[cur ^ 1][tid * 8]);
            gload_lds16(&Vt[(bhs * DKK + sr) * TT + kt + 64 + scol], &Vs[cur ^ 1][tid * 8]);
        }

        f32x4 s[4] = {};
        __builtin_amdgcn_s_setprio(1);
#pragma unroll
        for (int j = 0; j < 4; j++)
#pragma unroll
            for (int half = 0; half < 2; half++) {
                bf16x8 kf = *(bf16x8*)((char*)&Ks[cur][0] + (j * 16 + c) * 128 +
                                       (((unsigned)(half * 64 + g * 16)) ^ swz));
                s[j] = __builtin_amdgcn_mfma_f32_16x16x32_bf16(kf, qf[half], s[j], 0, 0, 0);
            }
        __builtin_amdgcn_s_setprio(0);
        // s[j][r] = z[kv = kt+j*16+g*4+r][q], already scaled by 0.125*log2e

        if (kt + 64 > sl) {                       // partial/masked tile only (block-uniform)
#pragma unroll
            for (int j = 0; j < 4; j++) {
                int kbase = kt + j * 16 + g * 4;
#pragma unroll
                for (int r = 0; r < 4; r++)
                    if (kbase + r >= sl) s[j][r] = -14427.0f;  // ~ -10000*log2e; exp2 -> 0
            }
        }

        float tmax = -INFINITY;
#pragma unroll
        for (int j = 0; j < 4; j++)
#pragma unroll
            for (int r = 0; r < 4; r++) tmax = fmaxf(tmax, s[j][r]);
        tmax = fmaxf(tmax, __shfl_xor(tmax, 16));
        tmax = fmaxf(tmax, __shfl_xor(tmax, 32));

        float p[4][4];
        float ps = 0.f;
        bool defer = __all(tmax <= m_ + 8.f);
        float mn = defer ? m_ : fmaxf(m_, tmax);
#pragma unroll
        for (int j = 0; j < 4; j++)
#pragma unroll
            for (int r = 0; r < 4; r++) {
                p[j][r] = __builtin_amdgcn_exp2f(s[j][r] - mn);
                ps += p[j][r];
            }
        ps += __shfl_xor(ps, 16);
        ps += __shfl_xor(ps, 32);
        if (defer) {
            l_ += ps;
        } else {
            float alpha = __builtin_amdgcn_exp2f(m_ - mn);
            l_ = l_ * alpha + ps;
            m_ = mn;
            float av[4];
#pragma unroll
            for (int r = 0; r < 4; r++) av[r] = __shfl(alpha, g * 4 + r);
#pragma unroll
            for (int go = 0; go < 4; go++)
#pragma unroll
                for (int r = 0; r < 4; r++) o[go][r] *= av[r];
        }

        // write P[q=c][kv = j*16+g*4 .. +3] as one b64, XOR-swizzled (per-wave buffer)
#pragma unroll
        for (int j = 0; j < 4; j++) {
            __hip_bfloat162 lo = __float22bfloat162_rn(make_float2(p[j][0], p[j][1]));
            __hip_bfloat162 hi = __float22bfloat162_rn(make_float2(p[j][2], p[j][3]));
            uint2 u;
            u.x = *(unsigned*)&lo;
            u.y = *(unsigned*)&hi;
            *(uint2*)(Pw + c * 128 + (((unsigned)(j * 32 + g * 8)) ^ swz)) = u;
        }
        // read A-fragments: P[q=c][kv = half*32 + g*8 .. +7] (same-wave dep, hw-ordered)
        bf16x8 pf0 = *(bf16x8*)(Pw + c * 128 + (((unsigned)(g * 16)) ^ swz));
        bf16x8 pf1 = *(bf16x8*)(Pw + c * 128 + (((unsigned)(64 + g * 16)) ^ swz));

        __builtin_amdgcn_s_setprio(1);
#pragma unroll
        for (int go = 0; go < 4; go++) {
            bf16x8 vf0 = *(bf16x8*)((char*)&Vs[cur][0] + (go * 16 + c) * 128 +
                                    (((unsigned)(g * 16)) ^ swz));
            o[go] = __builtin_amdgcn_mfma_f32_16x16x32_bf16(pf0, vf0, o[go], 0, 0, 0);
            bf16x8 vf1 = *(bf16x8*)((char*)&Vs[cur][0] + (go * 16 + c) * 128 +
                                    (((unsigned)(64 + g * 16)) ^ swz));
            o[go] = __builtin_amdgcn_mfma_f32_16x16x32_bf16(pf1, vf1, o[go], 0, 0, 0);
        }
        __builtin_amdgcn_s_setprio(0);
        cur ^= 1;
    }

    // final divide: l for q = g*4+r lives at lane (g*4+r)
    float linv[4];
#pragma unroll
    for (int r = 0; r < 4; r++) linv[r] = 1.f / __shfl(l_, g * 4 + r);
#pragma unroll
    for (int go = 0; go < 4; go++)
#pragma unroll
        for (int r = 0; r < 4; r++) {
            int t = q0 + w * 16 + g * 4 + r;
            int col = h * DKK + go * 16 + c;
            ctx[((size_t)(b * TT + t)) * HH + col] = f2bf(o[go][r] * linv[r]);
        }
}

// ---------------- row LayerNorm: reads x (bf16), writes d_out (fp32), eps=1e-12 ----------------
__global__ __launch_bounds__(256) void ln_kernel(const unsigned short* __restrict__ xb,
                                                 float* __restrict__ out,
                                                 const float* __restrict__ gam,
                                                 const float* __restrict__ bet) {
    int row = blockIdx.x, tid = threadIdx.x;
    ushort4 uv = reinterpret_cast<const ushort4*>(xb)[(size_t)row * 256 + tid];
    float x0 = bf2f(uv.x), x1 = bf2f(uv.y), x2 = bf2f(uv.z), x3 = bf2f(uv.w);
    float s = (x0 + x1) + (x2 + x3);
#pragma unroll
    for (int m = 1; m < 64; m <<= 1) s += __shfl_xor(s, m);
    __shared__ float red[4], red2[4];
    if ((tid & 63) == 0) red[tid >> 6] = s;
    __syncthreads();
    float mean = (red[0] + red[1] + red[2] + red[3]) * (1.f / 1024.f);
    float dx0 = x0 - mean, dx1 = x1 - mean, dx2 = x2 - mean, dx3 = x3 - mean;
    float ss = (dx0 * dx0 + dx1 * dx1) + (dx2 * dx2 + dx3 * dx3);
#pragma unroll
    for (int m = 1; m < 64; m <<= 1) ss += __shfl_xor(ss, m);
    if ((tid & 63) == 0) red2[tid >> 6] = ss;
    __syncthreads();
    float var = (red2[0] + red2[1] + red2[2] + red2[3]) * (1.f / 1024.f);
    float rs = rsqrtf(var + 1e-12f);
    int c = tid * 4;
    float4 ov;
    ov.x = dx0 * rs * gam[c + 0] + bet[c + 0];
    ov.y = dx1 * rs * gam[c + 1] + bet[c + 1];
    ov.z = dx2 * rs * gam[c + 2] + bet[c + 2];
    ov.w = dx3 * rs * gam[c + 3] + bet[c + 3];
    reinterpret_cast<float4*>(out)[(size_t)row * 256 + tid] = ov;
}

extern "C" void kernel_launch(void* const* d_in, const int* in_sizes, int n_in,
                              void* d_out, int out_size, void* d_ws, size_t ws_size,
                              hipStream_t stream) {
    const float* hid  = (const float*)d_in[0];
    const float* src  = (const float*)d_in[1];
    const int* slen   = (const int*)d_in[2];   // harness passes integers as int32
    const float* Wq  = (const float*)d_in[3];  const float* bq  = (const float*)d_in[4];
    const float* Wk  = (const float*)d_in[5];  const float* bk  = (const float*)d_in[6];
    const float* Wv  = (const float*)d_in[7];  const float* bv  = (const float*)d_in[8];
    const float* Wd  = (const float*)d_in[9];  const float* bd  = (const float*)d_in[10];
    const float* Wp1 = (const float*)d_in[11]; const float* bp1 = (const float*)d_in[12];
    const float* Wp2 = (const float*)d_in[13]; const float* bp2 = (const float*)d_in[14];
    const float* lng = (const float*)d_in[15]; const float* lnb = (const float*)d_in[16];

    // Workspace layout (bytes).
    char* ws = (char*)d_ws;
    const size_t MB = 1ull << 20;
    unsigned short* Wqt  = (unsigned short*)(ws + 0 * MB);
    unsigned short* Wkt  = (unsigned short*)(ws + 2 * MB);
    unsigned short* Wvt  = (unsigned short*)(ws + 4 * MB);
    unsigned short* Wdt  = (unsigned short*)(ws + 6 * MB);
    unsigned short* Wp1t = (unsigned short*)(ws + 8 * MB);
    unsigned short* Wp2t = (unsigned short*)(ws + 10 * MB);
    unsigned short* Kb   = (unsigned short*)(ws + 12 * MB);
    unsigned short* ctxb = (unsigned short*)(ws + 28 * MB);
    unsigned short* Vtb  = (unsigned short*)(ws + 44 * MB);
    unsigned short* Pb   = (unsigned short*)(ws + 60 * MB);
    unsigned short* Qb   = (unsigned short*)(ws + 76 * MB);
    unsigned short* Ptmp = ctxb;   // Wp1 output; dead after Pb is built, slot reused for ctx
    unsigned short* xb   = Kb;     // x = attn_out + hidden (bf16); Kb dead after attention

    // all 6 weight transposes in one dispatch (64x64 tiles, coalesced)
    wtcvt6_kernel<<<dim3(16, 16, 6), dim3(32, 8), 0, stream>>>(
        Wq, Wk, Wv, Wd, Wp1, Wp2, Wqt, Wkt, Wvt, Wdt, Wp1t, Wp2t);

    dim3 gg(8, 64);  // fixed (8,64) grid; in-kernel XCD tile swizzle
    // P = mask(relu(src@Wp1+bp1)@Wp2+bp2); rows >= ceil64(sl) are dead -> SKIP
    // src/hid converted fp32->bf16 inside the staging loop (F32A) — no separate cvt pass
    gemm_kernel<1, true, true><<<gg, 256, 0, stream>>>(nullptr, src, Wp1t, bp1, Ptmp, nullptr, nullptr, slen, BB * TT, HH, HH);
    gemm_kernel<2, true, false><<<gg, 256, 0, stream>>>(Ptmp, nullptr, Wp2t, bp2, Pb, nullptr, nullptr, slen, BB * TT, HH, HH);
    // Q (pre-scaled for base-2 softmax) all rows; K,V only live rows (separate dispatches —
    // GEMM fusion regressed twice, r7/r13)
    gemm_kernel<6, false, true><<<gg, 256, 0, stream>>>(nullptr, hid, Wqt, bq, Qb, nullptr, nullptr, slen, BB * TT, HH, HH);
    gemm_kernel<3, true, false><<<gg, 256, 0, stream>>>(Pb, nullptr, Wkt, bk, Kb, nullptr, nullptr, slen, BB * TT, HH, HH);
    gemm_kernel<4, true, false><<<gg, 256, 0, stream>>>(Pb, nullptr, Wvt, bv, Vtb, nullptr, nullptr, slen, BB * TT, HH, HH);
    // attention -> ctx (B,T,H) bf16
    attn_kernel<<<dim3(TT / 128, NHH, BB), 512, 0, stream>>>(Qb, Kb, Vtb, slen, ctxb);
    // x = ctx@Wd + bd + hidden -> xb (bf16; Kb slot now dead)
    gemm_kernel<5, false, false><<<gg, 256, 0, stream>>>(ctxb, nullptr, Wdt, bd, xb, nullptr, hid, slen, BB * TT, HH, HH);
    // LayerNorm: bf16 x -> fp32 d_out
    ln_kernel<<<BB * TT, 256, 0, stream>>>(xb, (float*)d_out, lng, lnb);
}

// Round 18
// 246.766 us; speedup vs baseline: 1.0137x; 1.0035x over previous
//
#include <hip/hip_runtime.h>
#include <hip/hip_bf16.h>

// Problem dims (fixed by the reference)
#define BB 4
#define TT 2048
#define HH 1024
#define NHH 16
#define DKK 64
// M = BB*TT = 8192, K = N = HH = 1024

typedef __attribute__((ext_vector_type(8))) short bf16x8;
typedef __attribute__((ext_vector_type(4))) float f32x4;

__device__ __forceinline__ unsigned short f2bf(float f) {
    union { float f; unsigned u; } v; v.f = f;
    unsigned r = v.u + 0x7fffu + ((v.u >> 16) & 1u);  // RNE
    return (unsigned short)(r >> 16);
}

__device__ __forceinline__ float bf2f(unsigned short u) {
    union { unsigned u; float f; } v; v.u = ((unsigned)u) << 16;
    return v.f;
}

__device__ __forceinline__ bf16x8 cvt8(const float* __restrict__ p) {
    float4 a = *(const float4*)p;
    float4 b = *(const float4*)(p + 4);
    bf16x8 r;
    r[0] = (short)f2bf(a.x); r[1] = (short)f2bf(a.y);
    r[2] = (short)f2bf(a.z); r[3] = (short)f2bf(a.w);
    r[4] = (short)f2bf(b.x); r[5] = (short)f2bf(b.y);
    r[6] = (short)f2bf(b.z); r[7] = (short)f2bf(b.w);
    return r;
}

// async global->LDS, 16B per lane; LDS dest must be linear in lane order
__device__ __forceinline__ void gload_lds16(const unsigned short* g, unsigned short* l) {
    __builtin_amdgcn_global_load_lds(
        (const __attribute__((address_space(1))) unsigned int*)g,
        (__attribute__((address_space(3))) unsigned int*)l, 16, 0, 0);
}

// 3-input max; clang fuses to v_max3_f32 on gfx9+
__device__ __forceinline__ float max3f(float a, float b, float c) {
    return fmaxf(fmaxf(a, b), c);
}

// ---------------- weight transpose + convert, all 6 weights, 64x64 tiles, coalesced ----------------
__global__ __launch_bounds__(256) void wtcvt6_kernel(
    const float* __restrict__ W0, const float* __restrict__ W1, const float* __restrict__ W2,
    const float* __restrict__ W3, const float* __restrict__ W4, const float* __restrict__ W5,
    unsigned short* __restrict__ T0, unsigned short* __restrict__ T1, unsigned short* __restrict__ T2,
    unsigned short* __restrict__ T3, unsigned short* __restrict__ T4, unsigned short* __restrict__ T5) {
    const float* W; unsigned short* Wt;
    switch (blockIdx.z) {
        case 0: W = W0; Wt = T0; break;
        case 1: W = W1; Wt = T1; break;
        case 2: W = W2; Wt = T2; break;
        case 3: W = W3; Wt = T3; break;
        case 4: W = W4; Wt = T4; break;
        default: W = W5; Wt = T5; break;
    }
    __shared__ float t[64][65];
    int bx = blockIdx.x * 64, by = blockIdx.y * 64;   // bx: n-range, by: k-range
    int tx = threadIdx.x, ty = threadIdx.y;           // block (32,8)
#pragma unroll
    for (int i = 0; i < 8; i++) {
        int kk = ty + 8 * i;
        float2 v = *(const float2*)&W[(size_t)(by + kk) * HH + bx + 2 * tx];
        t[kk][2 * tx] = v.x;
        t[kk][2 * tx + 1] = v.y;
    }
    __syncthreads();
#pragma unroll
    for (int i = 0; i < 8; i++) {
        int nn = ty + 8 * i;
        unsigned u = (unsigned)f2bf(t[2 * tx][nn]) | ((unsigned)f2bf(t[2 * tx + 1][nn]) << 16);
        *(unsigned*)&Wt[(size_t)(bx + nn) * HH + by + 2 * tx] = u;  // Wt[n][k] = W[k][n]
    }
}

// ---------------- MFMA GEMM (m97 structure): 128x128 tile, BK=64, global_load_lds w=16 ----------------
// Grid FIXED (8,64), in-kernel XCD tile swizzle. F32A: A fp32, reg-staged + converted.
// EPI: 1=relu->bf16  2=source-mask->bf16  3=head-split (K)  6=head-split * 0.125*log2e (Q)
//      4=transposed-head (V), operands swapped -> coalesced Vt store
//      5=+resid, x stored as BF16 (LN reads bf16 -> 32MB less HBM traffic)
template <int EPI, bool SKIP, bool F32A>
__global__ __launch_bounds__(256) void gemm_kernel(
    const unsigned short* __restrict__ A16, const float* __restrict__ A32,
    const unsigned short* __restrict__ Bt,
    const float* __restrict__ bias, unsigned short* __restrict__ Cb,
    float* __restrict__ Cf, const float* __restrict__ resid,
    const int* __restrict__ slen, int M, int N, int K) {
    __shared__ unsigned short As[128 * 64];   // [row][k] linear
    __shared__ unsigned short Bs[128 * 64];
    // XCD swizzle (bijective for 8x64 grid): xcd = flat&7 owns rows {xcd, xcd+8, ...}
    int flat = blockIdx.y * 8 + blockIdx.x;
    int xcd = flat & 7, idx = flat >> 3;
    int bx = (idx & 7) * 128;
    int by = (xcd + ((idx >> 3) << 3)) * 128;
    if constexpr (SKIP) {
        int slb = slen[by >> 11];
        int ktend = ((slb + 63) >> 6) << 6;
        if (ktend == 0) ktend = 64;           // attention still reads tile 0 (uniform-softmax case)
        if ((by & (TT - 1)) >= ktend) return; // whole 128-row tile dead (2048 % 128 == 0)
    }
    int tid = threadIdx.x, lane = tid & 63, w = tid >> 6;
    int wr = (w >> 1) * 64, wc = (w & 1) * 64;     // wave's 64x64 output quadrant

    f32x4 acc[4][4] = {};
    for (int k0 = 0; k0 < K; k0 += 64) {
        __syncthreads();
#pragma unroll
        for (int c = 0; c < 4; c++) {
            int idx2 = c * 256 + tid;
            int r = idx2 >> 3, col = (idx2 & 7) * 8;
            if constexpr (F32A) {
                *(bf16x8*)&As[idx2 * 8] = cvt8(&A32[(size_t)(by + r) * K + k0 + col]);
            } else {
                gload_lds16(&A16[(size_t)(by + r) * K + k0 + col], &As[idx2 * 8]);
            }
            gload_lds16(&Bt[(size_t)(bx + r) * K + k0 + col], &Bs[idx2 * 8]);
        }
        __syncthreads();  // drains vmcnt(0) + lgkmcnt
#pragma unroll
        for (int kk = 0; kk < 2; kk++) {
            bf16x8 a[4], b[4];
#pragma unroll
            for (int i = 0; i < 4; i++)
                a[i] = *(bf16x8*)&As[(wr + i * 16 + (lane & 15)) * 64 + kk * 32 + (lane >> 4) * 8];
#pragma unroll
            for (int j = 0; j < 4; j++)
                b[j] = *(bf16x8*)&Bs[(wc + j * 16 + (lane & 15)) * 64 + kk * 32 + (lane >> 4) * 8];
#pragma unroll
            for (int i = 0; i < 4; i++)
#pragma unroll
                for (int j = 0; j < 4; j++) {
                    if constexpr (EPI == 4)
                        acc[i][j] = __builtin_amdgcn_mfma_f32_16x16x32_bf16(b[j], a[i], acc[i][j], 0, 0, 0);
                    else
                        acc[i][j] = __builtin_amdgcn_mfma_f32_16x16x32_bf16(a[i], b[j], acc[i][j], 0, 0, 0);
                }
        }
    }

    int sl = 0;
    if constexpr (EPI == 2) sl = slen[by >> 11];  // 128-row tile never crosses a batch
#pragma unroll
    for (int i = 0; i < 4; i++)
#pragma unroll
        for (int j = 0; j < 4; j++)
#pragma unroll
            for (int r = 0; r < 4; r++) {
                if constexpr (EPI == 4) {
                    // swapped D: row-dim = n (from b[j]), col-dim = m (from a[i])
                    int nrow = bx + wc + j * 16 + (lane >> 4) * 4 + r;
                    int mcol = by + wr + i * 16 + (lane & 15);
                    float v = acc[i][j][r] + bias[nrow];
                    int b = mcol >> 11, t = mcol & (TT - 1), h = nrow >> 6, d = nrow & 63;
                    Cb[((size_t)((b * NHH + h) * DKK + d)) * TT + t] = f2bf(v);
                } else {
                    int row = by + wr + i * 16 + (lane >> 4) * 4 + r;
                    int col = bx + wc + j * 16 + (lane & 15);
                    float v = acc[i][j][r] + bias[col];
                    if constexpr (EPI == 1) v = fmaxf(v, 0.f);
                    if constexpr (EPI == 2) { int t = row & (TT - 1); if (t >= sl) v = 0.f; }
                    if constexpr (EPI == 6) v *= 0.18033688f;   // 0.125 * log2(e)
                    if constexpr (EPI == 1 || EPI == 2) {
                        Cb[(size_t)row * N + col] = f2bf(v);
                    } else if constexpr (EPI == 3 || EPI == 6) {
                        int b = row >> 11, t = row & (TT - 1), h = col >> 6, d = col & 63;
                        Cb[((size_t)((b * NHH + h) * TT + t)) * DKK + d] = f2bf(v);
                    } else if constexpr (EPI == 5) {
                        Cb[(size_t)row * N + col] = f2bf(v + resid[(size_t)row * N + col]);
                    }
                }
            }
}

// ---------------- flash attention: block = (b, h, 128 q-rows), 8 waves x 16 q-rows ----------------
// r17 config (61.7us) + T17: tmax reduction as nested 3-input maxes -> v_max3_f32
// (15 fmax -> 7 max3 + 1 max; VALU op-count cut on the softmax critical path).
__global__ __launch_bounds__(512, 6) void attn_kernel(
    const unsigned short* __restrict__ Q, const unsigned short* __restrict__ K,
    const unsigned short* __restrict__ Vt, const int* __restrict__ slen,
    unsigned short* __restrict__ ctx) {
    __shared__ unsigned short Ks[2][64 * 64];     // [kv][dk], XOR-swizzled content
    __shared__ unsigned short Vs[2][64 * 64];     // [dk][kv], XOR-swizzled content
    __shared__ unsigned short Pl[8][16 * 64];     // per-wave P [q][kv], XOR-swizzled
    int tid = threadIdx.x, lane = tid & 63, w = tid >> 6;
    int c = lane & 15, g = lane >> 4;
    int b = blockIdx.z, h = blockIdx.y, q0 = blockIdx.x * 128;
    size_t bhs = (size_t)(b * NHH + h);
    int sl = slen[b];
    int ktend = ((sl + 63) >> 6) << 6;
    if (ktend == 0) ktend = 64;                   // all-masked: one tile, uniform softmax -> bv

    bf16x8 qf[2];                                 // B-operand: Q[q = w*16+c][dk]
    int qrow = q0 + w * 16 + c;
#pragma unroll
    for (int half = 0; half < 2; half++)
        qf[half] = *(const bf16x8*)&Q[(bhs * TT + qrow) * DKK + half * 32 + g * 8];

    char* Pw = (char*)&Pl[w][0];
    unsigned swz = (unsigned)((c & 7) << 4);

    // staging coords: thread stages chunk (r = tid>>3, slot = tid&7) of both K and V;
    // source slot pre-swizzled so LDS[r][s] = G[r][s ^ (r&7)]
    int sr = tid >> 3, ss = tid & 7;
    int scol = (ss ^ (sr & 7)) * 8;

    // prologue: issue tile-0 loads into buffer 0 (drained by the loop's first barrier)
    gload_lds16(&K[(bhs * TT + sr) * DKK + scol], &Ks[0][tid * 8]);
    gload_lds16(&Vt[(bhs * DKK + sr) * TT + scol], &Vs[0][tid * 8]);
    int cur = 0;

    float m_ = -INFINITY, l_ = 0.f;               // state for q-row (w*16 + c), log2 domain
    f32x4 o[4] = {};                              // O[q = g*4+r][d = go*16+c]

    for (int kt = 0; kt < ktend; kt += 64) {
        __syncthreads();   // drains vmcnt -> buf[cur] ready; all waves done reading buf[cur^1]
        if (kt + 64 < ktend) {                    // prefetch next tile into the other buffer
            gload_lds16(&K[(bhs * TT + kt + 64 + sr) * DKK + scol], &Ks[cur ^ 1][tid * 8]);
            gload_lds16(&Vt[(bhs * DKK + sr) * TT + kt + 64 + scol], &Vs[cur ^ 1][tid * 8]);
        }

        f32x4 s[4] = {};
        __builtin_amdgcn_s_setprio(1);
#pragma unroll
        for (int j = 0; j < 4; j++)
#pragma unroll
            for (int half = 0; half < 2; half++) {
                bf16x8 kf = *(bf16x8*)((char*)&Ks[cur][0] + (j * 16 + c) * 128 +
                                       (((unsigned)(half * 64 + g * 16)) ^ swz));
                s[j] = __builtin_amdgcn_mfma_f32_16x16x32_bf16(kf, qf[half], s[j], 0, 0, 0);
            }
        __builtin_amdgcn_s_setprio(0);
        // s[j][r] = z[kv = kt+j*16+g*4+r][q], already scaled by 0.125*log2e

        if (kt + 64 > sl) {                       // partial/masked tile only (block-uniform)
#pragma unroll
            for (int j = 0; j < 4; j++) {
                int kbase = kt + j * 16 + g * 4;
#pragma unroll
                for (int r = 0; r < 4; r++)
                    if (kbase + r >= sl) s[j][r] = -14427.0f;  // ~ -10000*log2e; exp2 -> 0
            }
        }

        // 16-element max via v_max3 chain: 7 max3 + 1 max (was 15 serial fmax)
        float tmax = max3f(s[0][0], s[0][1], s[0][2]);
        tmax = max3f(tmax, s[0][3], s[1][0]);
        tmax = max3f(tmax, s[1][1], s[1][2]);
        tmax = max3f(tmax, s[1][3], s[2][0]);
        tmax = max3f(tmax, s[2][1], s[2][2]);
        tmax = max3f(tmax, s[2][3], s[3][0]);
        tmax = max3f(tmax, s[3][1], s[3][2]);
        tmax = fmaxf(tmax, s[3][3]);
        tmax = fmaxf(tmax, __shfl_xor(tmax, 16));
        tmax = fmaxf(tmax, __shfl_xor(tmax, 32));

        float p[4][4];
        float ps = 0.f;
        bool defer = __all(tmax <= m_ + 8.f);
        float mn = defer ? m_ : fmaxf(m_, tmax);
#pragma unroll
        for (int j = 0; j < 4; j++)
#pragma unroll
            for (int r = 0; r < 4; r++) {
                p[j][r] = __builtin_amdgcn_exp2f(s[j][r] - mn);
                ps += p[j][r];
            }
        ps += __shfl_xor(ps, 16);
        ps += __shfl_xor(ps, 32);
        if (defer) {
            l_ += ps;
        } else {
            float alpha = __builtin_amdgcn_exp2f(m_ - mn);
            l_ = l_ * alpha + ps;
            m_ = mn;
            float av[4];
#pragma unroll
            for (int r = 0; r < 4; r++) av[r] = __shfl(alpha, g * 4 + r);
#pragma unroll
            for (int go = 0; go < 4; go++)
#pragma unroll
                for (int r = 0; r < 4; r++) o[go][r] *= av[r];
        }

        // write P[q=c][kv = j*16+g*4 .. +3] as one b64, XOR-swizzled (per-wave buffer)
#pragma unroll
        for (int j = 0; j < 4; j++) {
            __hip_bfloat162 lo = __float22bfloat162_rn(make_float2(p[j][0], p[j][1]));
            __hip_bfloat162 hi = __float22bfloat162_rn(make_float2(p[j][2], p[j][3]));
            uint2 u;
            u.x = *(unsigned*)&lo;
            u.y = *(unsigned*)&hi;
            *(uint2*)(Pw + c * 128 + (((unsigned)(j * 32 + g * 8)) ^ swz)) = u;
        }
        // read A-fragments: P[q=c][kv = half*32 + g*8 .. +7] (same-wave dep, hw-ordered)
        bf16x8 pf0 = *(bf16x8*)(Pw + c * 128 + (((unsigned)(g * 16)) ^ swz));
        bf16x8 pf1 = *(bf16x8*)(Pw + c * 128 + (((unsigned)(64 + g * 16)) ^ swz));

        __builtin_amdgcn_s_setprio(1);
#pragma unroll
        for (int go = 0; go < 4; go++) {
            bf16x8 vf0 = *(bf16x8*)((char*)&Vs[cur][0] + (go * 16 + c) * 128 +
                                    (((unsigned)(g * 16)) ^ swz));
            o[go] = __builtin_amdgcn_mfma_f32_16x16x32_bf16(pf0, vf0, o[go], 0, 0, 0);
            bf16x8 vf1 = *(bf16x8*)((char*)&Vs[cur][0] + (go * 16 + c) * 128 +
                                    (((unsigned)(64 + g * 16)) ^ swz));
            o[go] = __builtin_amdgcn_mfma_f32_16x16x32_bf16(pf1, vf1, o[go], 0, 0, 0);
        }
        __builtin_amdgcn_s_setprio(0);
        cur ^= 1;
    }

    // final divide: l for q = g*4+r lives at lane (g*4+r)
    float linv[4];
#pragma unroll
    for (int r = 0; r < 4; r++) linv[r] = 1.f / __shfl(l_, g * 4 + r);
#pragma unroll
    for (int go = 0; go < 4; go++)
#pragma unroll
        for (int r = 0; r < 4; r++) {
            int t = q0 + w * 16 + g * 4 + r;
            int col = h * DKK + go * 16 + c;
            ctx[((size_t)(b * TT + t)) * HH + col] = f2bf(o[go][r] * linv[r]);
        }
}

// ---------------- row LayerNorm: reads x (bf16), writes d_out (fp32), eps=1e-12 ----------------
__global__ __launch_bounds__(256) void ln_kernel(const unsigned short* __restrict__ xb,
                                                 float* __restrict__ out,
                                                 const float* __restrict__ gam,
                                                 const float* __restrict__ bet) {
    int row = blockIdx.x, tid = threadIdx.x;
    ushort4 uv = reinterpret_cast<const ushort4*>(xb)[(size_t)row * 256 + tid];
    float x0 = bf2f(uv.x), x1 = bf2f(uv.y), x2 = bf2f(uv.z), x3 = bf2f(uv.w);
    float s = (x0 + x1) + (x2 + x3);
#pragma unroll
    for (int m = 1; m < 64; m <<= 1) s += __shfl_xor(s, m);
    __shared__ float red[4], red2[4];
    if ((tid & 63) == 0) red[tid >> 6] = s;
    __syncthreads();
    float mean = (red[0] + red[1] + red[2] + red[3]) * (1.f / 1024.f);
    float dx0 = x0 - mean, dx1 = x1 - mean, dx2 = x2 - mean, dx3 = x3 - mean;
    float ss = (dx0 * dx0 + dx1 * dx1) + (dx2 * dx2 + dx3 * dx3);
#pragma unroll
    for (int m = 1; m < 64; m <<= 1) ss += __shfl_xor(ss, m);
    if ((tid & 63) == 0) red2[tid >> 6] = ss;
    __syncthreads();
    float var = (red2[0] + red2[1] + red2[2] + red2[3]) * (1.f / 1024.f);
    float rs = rsqrtf(var + 1e-12f);
    int c = tid * 4;
    float4 ov;
    ov.x = dx0 * rs * gam[c + 0] + bet[c + 0];
    ov.y = dx1 * rs * gam[c + 1] + bet[c + 1];
    ov.z = dx2 * rs * gam[c + 2] + bet[c + 2];
    ov.w = dx3 * rs * gam[c + 3] + bet[c + 3];
    reinterpret_cast<float4*>(out)[(size_t)row * 256 + tid] = ov;
}

extern "C" void kernel_launch(void* const* d_in, const int* in_sizes, int n_in,
                              void* d_out, int out_size, void* d_ws, size_t ws_size,
                              hipStream_t stream) {
    const float* hid  = (const float*)d_in[0];
    const float* src  = (const float*)d_in[1];
    const int* slen   = (const int*)d_in[2];   // harness passes integers as int32
    const float* Wq  = (const float*)d_in[3];  const float* bq  = (const float*)d_in[4];
    const float* Wk  = (const float*)d_in[5];  const float* bk  = (const float*)d_in[6];
    const float* Wv  = (const float*)d_in[7];  const float* bv  = (const float*)d_in[8];
    const float* Wd  = (const float*)d_in[9];  const float* bd  = (const float*)d_in[10];
    const float* Wp1 = (const float*)d_in[11]; const float* bp1 = (const float*)d_in[12];
    const float* Wp2 = (const float*)d_in[13]; const float* bp2 = (const float*)d_in[14];
    const float* lng = (const float*)d_in[15]; const float* lnb = (const float*)d_in[16];

    // Workspace layout (bytes).
    char* ws = (char*)d_ws;
    const size_t MB = 1ull << 20;
    unsigned short* Wqt  = (unsigned short*)(ws + 0 * MB);
    unsigned short* Wkt  = (unsigned short*)(ws + 2 * MB);
    unsigned short* Wvt  = (unsigned short*)(ws + 4 * MB);
    unsigned short* Wdt  = (unsigned short*)(ws + 6 * MB);
    unsigned short* Wp1t = (unsigned short*)(ws + 8 * MB);
    unsigned short* Wp2t = (unsigned short*)(ws + 10 * MB);
    unsigned short* Kb   = (unsigned short*)(ws + 12 * MB);
    unsigned short* ctxb = (unsigned short*)(ws + 28 * MB);
    unsigned short* Vtb  = (unsigned short*)(ws + 44 * MB);
    unsigned short* Pb   = (unsigned short*)(ws + 60 * MB);
    unsigned short* Qb   = (unsigned short*)(ws + 76 * MB);
    unsigned short* Ptmp = ctxb;   // Wp1 output; dead after Pb is built, slot reused for ctx
    unsigned short* xb   = Kb;     // x = attn_out + hidden (bf16); Kb dead after attention

    // all 6 weight transposes in one dispatch (64x64 tiles, coalesced)
    wtcvt6_kernel<<<dim3(16, 16, 6), dim3(32, 8), 0, stream>>>(
        Wq, Wk, Wv, Wd, Wp1, Wp2, Wqt, Wkt, Wvt, Wdt, Wp1t, Wp2t);

    dim3 gg(8, 64);  // fixed (8,64) grid; in-kernel XCD tile swizzle
    // P = mask(relu(src@Wp1+bp1)@Wp2+bp2); rows >= ceil64(sl) are dead -> SKIP
    // src/hid converted fp32->bf16 inside the staging loop (F32A) — no separate cvt pass
    gemm_kernel<1, true, true><<<gg, 256, 0, stream>>>(nullptr, src, Wp1t, bp1, Ptmp, nullptr, nullptr, slen, BB * TT, HH, HH);
    gemm_kernel<2, true, false><<<gg, 256, 0, stream>>>(Ptmp, nullptr, Wp2t, bp2, Pb, nullptr, nullptr, slen, BB * TT, HH, HH);
    // Q (pre-scaled for base-2 softmax) all rows; K,V only live rows (separate dispatches —
    // GEMM fusion regressed twice, r7/r13)
    gemm_kernel<6, false, true><<<gg, 256, 0, stream>>>(nullptr, hid, Wqt, bq, Qb, nullptr, nullptr, slen, BB * TT, HH, HH);
    gemm_kernel<3, true, false><<<gg, 256, 0, stream>>>(Pb, nullptr, Wkt, bk, Kb, nullptr, nullptr, slen, BB * TT, HH, HH);
    gemm_kernel<4, true, false><<<gg, 256, 0, stream>>>(Pb, nullptr, Wvt, bv, Vtb, nullptr, nullptr, slen, BB * TT, HH, HH);
    // attention -> ctx (B,T,H) bf16
    attn_kernel<<<dim3(TT / 128, NHH, BB), 512, 0, stream>>>(Qb, Kb, Vtb, slen, ctxb);
    // x = ctx@Wd + bd + hidden -> xb (bf16; Kb slot now dead)
    gemm_kernel<5, false, false><<<gg, 256, 0, stream>>>(ctxb, nullptr, Wdt, bd, xb, nullptr, hid, slen, BB * TT, HH, HH);
    // LayerNorm: bf16 x -> fp32 d_out
    ln_kernel<<<BB * TT, 256, 0, stream>>>(xb, (float*)d_out, lng, lnb);
}